// Round 10
// baseline (315.525 us; speedup 1.0000x reference)
//
#include <hip/hip_runtime.h>

#define DIM 128
#define MROW 272   // LDS bf16 m-tile row stride in bytes
#define ECAP 256   // per-engine staged edge capacity (ints)

typedef unsigned int uint32;
typedef short bf16x8 __attribute__((ext_vector_type(8)));
typedef float f32x4 __attribute__((ext_vector_type(4)));

__device__ __forceinline__ unsigned short f2b(float f) {
    return (unsigned short)((__float_as_uint(f) + 0x8000u) >> 16);
}
__device__ __forceinline__ uint32 packbf2(float lo, float hi) {
    uint32 a = __float_as_uint(lo);
    uint32 b = __float_as_uint(hi);
    return ((a + 0x8000u) >> 16) | ((b + 0x8000u) & 0xffff0000u);
}
__device__ __forceinline__ float bflo(uint32 u) { return __uint_as_float(u << 16); }
__device__ __forceinline__ float bfhi(uint32 u) { return __uint_as_float(u & 0xffff0000u); }

// ---------------- degree count ----------------
__global__ __launch_bounds__(256) void k_count(const int* __restrict__ dst,
                                               int* __restrict__ cnt, int E) {
    int e = blockIdx.x * 256 + threadIdx.x;
    if (e < E) atomicAdd(&cnt[dst[e]], 1);
}

// g0 = dinv ⊙ x (bf16-packed); also zero sentinel rows g0[n], g1[n] and dinv[n]
__global__ __launch_bounds__(256) void k_scaleg(const float* __restrict__ x,
                                                float* __restrict__ dinv,
                                                uint32* __restrict__ g,
                                                uint32* __restrict__ g1, int n) {
    int t = blockIdx.x * 256 + threadIdx.x;
    if (blockIdx.x == 0 && threadIdx.x < 64) {
        g [(size_t)n * 64 + threadIdx.x] = 0u;
        g1[(size_t)n * 64 + threadIdx.x] = 0u;
        if (threadIdx.x == 0) dinv[n] = 0.f;
    }
    if (t >= n * 64) return;
    int node = t >> 6;
    float dv = dinv[node];
    float2 v = ((const float2*)x)[t];
    g[t] = packbf2(dv * v.x, dv * v.y);
}

// ---------------- scan (+dinv fused) ----------------
__global__ __launch_bounds__(256) void k_scan1(const int* __restrict__ cnt,
                                               int* __restrict__ incl,
                                               int* __restrict__ bsums,
                                               float* __restrict__ dinv, int n) {
    __shared__ int tmp[256];
    int i = blockIdx.x * 256 + threadIdx.x;
    int t = threadIdx.x;
    int c = (i < n) ? cnt[i] : 0;
    if (i < n) dinv[i] = rsqrtf((float)(c + 1));
    tmp[t] = c;
    __syncthreads();
#pragma unroll
    for (int off = 1; off < 256; off <<= 1) {
        int v = (t >= off) ? tmp[t - off] : 0;
        __syncthreads();
        tmp[t] += v;
        __syncthreads();
    }
    if (i < n) incl[i] = tmp[t];
    if (t == 255) bsums[blockIdx.x] = tmp[255];
}

__global__ __launch_bounds__(512) void k_scan2(int* __restrict__ bsums, int nb) {
    __shared__ int tmp[512];
    int t = threadIdx.x;
    tmp[t] = (t < nb) ? bsums[t] : 0;
    __syncthreads();
#pragma unroll
    for (int off = 1; off < 512; off <<= 1) {
        int v = (t >= off) ? tmp[t - off] : 0;
        __syncthreads();
        tmp[t] += v;
        __syncthreads();
    }
    if (t < nb) bsums[t] = (t == 0) ? 0 : tmp[t - 1];
}

__global__ __launch_bounds__(256) void k_scan3(int* __restrict__ incl,
                                               const int* __restrict__ bsums, int n) {
    int i = blockIdx.x * 256 + threadIdx.x;
    if (i < n) incl[i] += bsums[blockIdx.x];
}

// ---------------- CSR fill ----------------
__global__ __launch_bounds__(256) void k_fill(const int* __restrict__ src,
                                              const int* __restrict__ dst,
                                              int* __restrict__ incl,
                                              int* __restrict__ srcs, int E) {
    int e = blockIdx.x * 256 + threadIdx.x;
    if (e >= E) return;
    int p = atomicSub(&incl[dst[e]], 1) - 1;
    srcs[p] = src[e];
}

// ---------------- W -> per-lane bf16 B-fragments ----------------
__global__ __launch_bounds__(256) void k_prepW(const float* __restrict__ Ws,
                                               short* __restrict__ Wb, int total) {
    int t = blockIdx.x * 256 + threadIdx.x;
    if (t >= total) return;
    int layer = t >> 14;
    int idx = t & 16383;
    int j = idx & 7;
    int l = (idx >> 3) & 63;
    int f = idx >> 9;
    int ks = f & 3;
    int cs = (f >> 2) & 1;
    int w = f >> 3;
    int nn = w * 32 + cs * 16 + (l & 15);
    int kk = ks * 32 + (l >> 4) * 8 + j;
    Wb[t] = (short)f2b(Ws[(size_t)layer * DIM * DIM + kk * DIM + nn]);
}

// ---------------- fused layer v4 ----------------
// phase 0: rowS + per-engine edge lists staged to LDS (sentinel-padded).
// phase 1: 8 half-wave engines x 2 interleaved pairs; batch-8 gathers, indices
//          from LDS broadcast ds_read, sentinel row kills masks; 32-bit saddr.
// phase 2: B-fragments + MFMA -> g_next | out.
__global__ __launch_bounds__(256) void k_layer(const uint32* __restrict__ g,
                                               const int* __restrict__ srcs,
                                               const int* __restrict__ rowptr,
                                               const float* __restrict__ dinv,
                                               const short* __restrict__ Wb,
                                               const float* __restrict__ bias,
                                               uint32* __restrict__ Gn,
                                               float* __restrict__ Out,
                                               int n, int E, int final_layer) {
    __shared__ __align__(16) char smem[32 * MROW];   // 8.5 KB bf16 tile
    __shared__ int eL[8][ECAP];                      // 8 KB staged edges
    __shared__ int rowS[33];
    int tid = threadIdx.x;
    int w = tid >> 6;
    int lane = tid & 63;
    int row0 = blockIdx.x * 32;

    if (tid < 33) {
        int r = row0 + tid;
        rowS[tid] = (r < n) ? rowptr[r] : E;
    }
    __syncthreads();

    // ---- phase 1 ----
    {
        int hw = tid >> 5;
        int sub = tid & 31;
        int base4 = hw * 4;
        int p0 = rowS[base4];
        int cnt = rowS[base4 + 4] - p0;
        bool useL = (cnt <= ECAP - 8);
        if (useL) {
            for (int j = sub; j < cnt; j += 32) eL[hw][j] = srcs[p0 + j];
            if (sub < 8) eL[hw][cnt + sub] = n;     // sentinel pad
        }
        // engine consumes its own LDS writes: wave-level lgkm waits suffice (no barrier)

        const char* gB = (const char*)g;
        uint32 subOff = (uint32)(sub << 3);
        int Em1 = E - 1;

#pragma unroll
        for (int i = 0; i < 2; ++i) {
            int nlA = base4 + 2 * i;
            int nlB = nlA + 1;
            int pA = rowS[nlA] - p0, qA = rowS[nlA + 1] - p0;
            int pB = qA,              qB = rowS[nlB + 1] - p0;
            int nodeA = min(row0 + nlA, n);
            int nodeB = min(row0 + nlB, n);
            float dA = dinv[nodeA];
            float dB = dinv[nodeB];
            uint2 uA = *(const uint2*)(gB + (((uint32)nodeA) << 8) + subOff);
            uint2 uB = *(const uint2*)(gB + (((uint32)nodeB) << 8) + subOff);
            float aA0 = bflo(uA.x), aA1 = bfhi(uA.x), aA2 = bflo(uA.y), aA3 = bfhi(uA.y);
            float aB0 = bflo(uB.x), aB1 = bfhi(uB.x), aB2 = bflo(uB.y), aB3 = bfhi(uB.y);
            int nb = max(qA - pA, qB - pB);

#define GLOOP(FETCH)                                                      \
            for (int t = 0; t < nb; t += 8) {                             \
                uint2 vA[8], vB[8];                                       \
                _Pragma("unroll")                                         \
                for (int u = 0; u < 8; ++u) {                             \
                    int eA = pA + t + u;                                  \
                    int eB = pB + t + u;                                  \
                    int iA = FETCH(eA);                                   \
                    int iB = FETCH(eB);                                   \
                    iA = (eA < qA) ? iA : n;                              \
                    iB = (eB < qB) ? iB : n;                              \
                    vA[u] = *(const uint2*)(gB + (((uint32)iA) << 8) + subOff); \
                    vB[u] = *(const uint2*)(gB + (((uint32)iB) << 8) + subOff); \
                }                                                         \
                _Pragma("unroll")                                         \
                for (int u = 0; u < 8; ++u) {                             \
                    aA0 += bflo(vA[u].x); aA1 += bfhi(vA[u].x);           \
                    aA2 += bflo(vA[u].y); aA3 += bfhi(vA[u].y);           \
                    aB0 += bflo(vB[u].x); aB1 += bfhi(vB[u].x);           \
                    aB2 += bflo(vB[u].y); aB3 += bfhi(vB[u].y);           \
                }                                                         \
            }

#define FETCH_LDS(e) (eL[hw][(e)])
#define FETCH_GLB(e) (srcs[min(p0 + (e), Em1)])
            if (useL) { GLOOP(FETCH_LDS) } else { GLOOP(FETCH_GLB) }
#undef FETCH_LDS
#undef FETCH_GLB
#undef GLOOP

            uint2 oA, oB;
            oA.x = packbf2(dA * aA0, dA * aA1);
            oA.y = packbf2(dA * aA2, dA * aA3);
            oB.x = packbf2(dB * aB0, dB * aB1);
            oB.y = packbf2(dB * aB2, dB * aB3);
            *(uint2*)(smem + nlA * MROW + sub * 8) = oA;
            *(uint2*)(smem + nlB * MROW + sub * 8) = oB;
        }
    }
    __syncthreads();
    __builtin_amdgcn_sched_barrier(0);   // keep B-frag loads out of phase 1 (VGPR cap)

    // ---- phase 2: B-fragments + MFMA ----
    const bf16x8* wb = (const bf16x8*)Wb;
    bf16x8 bfrag[2][4];
#pragma unroll
    for (int cs = 0; cs < 2; ++cs)
#pragma unroll
        for (int ks = 0; ks < 4; ++ks)
            bfrag[cs][ks] = wb[((w * 2 + cs) * 4 + ks) * 64 + lane];

    int lr = lane & 15;
    int lg = lane >> 4;

    f32x4 acc[2][2];
#pragma unroll
    for (int rs = 0; rs < 2; ++rs)
#pragma unroll
        for (int cs = 0; cs < 2; ++cs) acc[rs][cs] = (f32x4){0.f, 0.f, 0.f, 0.f};

    const char* base0 = smem + lr * MROW + lg * 16;
    const char* base1 = smem + (16 + lr) * MROW + lg * 16;
#pragma unroll
    for (int ks = 0; ks < 4; ++ks) {
        bf16x8 a0 = *(const bf16x8*)(base0 + ks * 64);
        bf16x8 a1 = *(const bf16x8*)(base1 + ks * 64);
#pragma unroll
        for (int cs = 0; cs < 2; ++cs) {
            acc[0][cs] = __builtin_amdgcn_mfma_f32_16x16x32_bf16(a0, bfrag[cs][ks], acc[0][cs], 0, 0, 0);
            acc[1][cs] = __builtin_amdgcn_mfma_f32_16x16x32_bf16(a1, bfrag[cs][ks], acc[1][cs], 0, 0, 0);
        }
    }

    float b0 = bias[w * 32 + lr];
    float b1 = bias[w * 32 + 16 + lr];

    // C/D layout (m89-verified): col = l&15, row = (l>>4)*4 + reg
#pragma unroll
    for (int rs = 0; rs < 2; ++rs)
#pragma unroll
        for (int r = 0; r < 4; ++r) {
            int grow = row0 + rs * 16 + lg * 4 + r;
            if (grow < n) {
                float h0 = fmaxf(acc[rs][0][r] + b0, 0.f);
                float h1 = fmaxf(acc[rs][1][r] + b1, 0.f);
                if (final_layer) {
                    Out[(size_t)grow * DIM + w * 32 + lr]      = h0;
                    Out[(size_t)grow * DIM + w * 32 + 16 + lr] = h1;
                } else {
                    float dv = dinv[grow];
                    unsigned short* gp = (unsigned short*)Gn;
                    gp[(size_t)grow * DIM + w * 32 + lr]      = f2b(dv * h0);
                    gp[(size_t)grow * DIM + w * 32 + 16 + lr] = f2b(dv * h1);
                }
            }
        }
}

extern "C" void kernel_launch(void* const* d_in, const int* in_sizes, int n_in,
                              void* d_out, int out_size, void* d_ws, size_t ws_size,
                              hipStream_t stream) {
    const float* x  = (const float*)d_in[0];
    const int*   ei = (const int*)d_in[1];
    const float* Ws = (const float*)d_in[2];
    const float* bs = (const float*)d_in[3];

    const int N = in_sizes[0] / DIM;           // 100000
    const int E = in_sizes[1] / 2;             // 640000
    const int L = in_sizes[2] / (DIM * DIM);   // 3

    const int* src = ei;
    const int* dst = ei + E;

    float* out = (float*)d_out;

    char* ws = (char*)d_ws;
    uint32* g0   = (uint32*)ws;                ws += (size_t)(N + 1) * 64 * 4;  // +sentinel row
    uint32* g1   = (uint32*)ws;                ws += (size_t)(N + 1) * 64 * 4;
    short* Wb    = (short*)ws;                 ws += (size_t)L * 16384 * 2;
    float* dinv  = (float*)ws;                 ws += (size_t)(N + 1) * 4;       // +dinv[n]=0
    int*   cnt   = (int*)ws;                   ws += (size_t)N * 4;
    int*   incl  = (int*)ws;                   ws += (size_t)N * 4;
    int*   srcs  = (int*)ws;                   ws += (size_t)E * 4;
    int*   bsums = (int*)ws;                   ws += 512 * 4;

    const int nbN = (N + 255) / 256;           // 391 (< 512)
    const int nbE = (E + 255) / 256;
    const int totW = L * 16384;

    // ---- prepass ----
    k_prepW<<<(totW + 255) / 256, 256, 0, stream>>>(Ws, Wb, totW);
    hipMemsetAsync(cnt, 0, (size_t)N * 4, stream);
    k_count<<<nbE, 256, 0, stream>>>(dst, cnt, E);
    k_scan1<<<nbN, 256, 0, stream>>>(cnt, incl, bsums, dinv, N);
    k_scan2<<<1, 512, 0, stream>>>(bsums, nbN);
    k_scaleg<<<(N * 64 + 255) / 256, 256, 0, stream>>>(x, dinv, g0, g1, N);
    k_scan3<<<nbN, 256, 0, stream>>>(incl, bsums, N);
    k_fill <<<nbE, 256, 0, stream>>>(src, dst, incl, srcs, E);

    // ---- fused layers ----
    const int nblk = (N + 31) / 32;
    uint32* gin = g0;
    for (int l = 0; l < L; ++l) {
        uint32* gout = (gin == g0) ? g1 : g0;
        k_layer<<<nblk, 256, 0, stream>>>(gin, srcs, incl, dinv,
                                          Wb + (size_t)l * 16384,
                                          bs + (size_t)l * DIM,
                                          gout, out, N, E, l == L - 1);
        gin = gout;
    }
}